// Round 1
// 15071.666 us; speedup vs baseline: 1.2181x; 1.2181x over previous
//
#include <hip/hip_runtime.h>

// HierarchicalLstmDecoder on MI355X (gfx950).
// B=128, S=16, L=16, T=256, Z=512, HC=1024, E=512, HD=1024, V=1024.
// v2: persistent grid-resident recurrence kernels with device-scope grid barriers.
//  - conductor: 1 kernel, 16 phases (was 16 launches)
//  - decoder: layer0+layer1 fused, 1-step skew pipeline, 4 chunk kernels x 65 phases
//    (was 512 launches + 4 batched h0@W1ih GEMMs, now folded into per-step K=2048)
//  - gate-strip decomposition: WG owns 16 hidden cols x 4 gate strips -> all 4 gate
//    values for (row, j) land in one lane's registers; c-state stays in VGPRs.

typedef float  floatx4 __attribute__((ext_vector_type(4)));
typedef __bf16 bf16x8  __attribute__((ext_vector_type(8)));
typedef unsigned short u16;

#define MFMA16(a, b, c) __builtin_amdgcn_mfma_f32_16x16x32_bf16(a, b, c, 0, 0, 0)

__device__ __forceinline__ u16 f2b(float f) {
  unsigned int u = __float_as_uint(f);
  u += 0x7fffu + ((u >> 16) & 1u);            // RNE
  return (u16)(u >> 16);
}
__device__ __forceinline__ float sigf(float x) { return 1.f / (1.f + __expf(-x)); }
__device__ __forceinline__ float tanhf_fast(float x) {
  float e = __expf(-2.f * fabsf(x));
  float r = (1.f - e) / (1.f + e);
  return x >= 0.f ? r : -r;
}

// Device-scope grid barrier: monotonic counter, release-add / relaxed-poll / acquire-fence.
// Relaxed agent-scope atomic loads bypass L1/L2 (fresh value) without per-poll invalidates.
__device__ __forceinline__ void gridbar(unsigned* bar, unsigned target) {
  __syncthreads();
  if (threadIdx.x == 0) {
    __hip_atomic_fetch_add(bar, 1u, __ATOMIC_RELEASE, __HIP_MEMORY_SCOPE_AGENT);
    while (__hip_atomic_load(bar, __ATOMIC_RELAXED, __HIP_MEMORY_SCOPE_AGENT) < target)
      __builtin_amdgcn_s_sleep(2);
    __builtin_amdgcn_fence(__ATOMIC_ACQUIRE, "agent");
  }
  __syncthreads();
}

// ---------------- casts ----------------
__global__ void cast_f2b(const float* __restrict__ s, u16* __restrict__ d, int n4) {
  int i = blockIdx.x * blockDim.x + threadIdx.x;
  if (i < n4) {
    float4 v = ((const float4*)s)[i];
    u16* o = d + (size_t)i * 4;
    o[0] = f2b(v.x); o[1] = f2b(v.y); o[2] = f2b(v.z); o[3] = f2b(v.w);
  }
}

// d[r*dstride + doff + c] = bf16(s[r*sstride + soff + c]); c in [0, 2^clog2)
__global__ void cast_slice2(const float* __restrict__ s, u16* __restrict__ d,
                            int sstride, int soff, int dstride, int doff, int clog2) {
  int idx = blockIdx.x * blockDim.x + threadIdx.x;
  int r = idx >> clog2;
  int c = idx & ((1 << clog2) - 1);
  d[(size_t)r * dstride + doff + c] = f2b(s[(size_t)r * sstride + soff + c]);
}

// ---------------- generic GEMM:  C[M,N] = act(A @ W^T + b1 + b2) ----------------
// AMODE 0: arow = r (A row stride = K).
// AMODE 1: r=(b,tt) b=r>>6, tt=r&63; t=t0+tt; arow=b*256+t-SHIFT (zeros when SHIFT && t==0).
// AMODE 2: r=(b,t) b=r>>8, t=r&255; A element offset = (t+1)*(128*2048) + b*2048 + 1024
//          (reads h1[t] out of the interleaved hslots buffer; K must be 1024).
template <int AMODE, int SHIFT, int ACT>
__global__ __launch_bounds__(256) void gemm_kernel(
    const u16* __restrict__ A, const u16* __restrict__ W,
    const float* __restrict__ b1, const float* __restrict__ b2,
    float* __restrict__ Cf, u16* __restrict__ Cb,
    int M, int N, int K, int t0) {
  int tid = threadIdx.x;
  int lane = tid & 63, wave = tid >> 6;
  int lr = lane & 15, lk = (lane >> 4) * 8;
  int mblk = blockIdx.y * 128 + (wave >> 1) * 64;
  int nblk = blockIdx.x * 128 + (wave & 1) * 64;

  bf16x8 zf;
#pragma unroll
  for (int q = 0; q < 8; ++q) zf[q] = (__bf16)0.f;

  const u16* ap[4];
  bool aval[4];
#pragma unroll
  for (int i = 0; i < 4; ++i) {
    int r = mblk + i * 16 + lr;
    bool v = true;
    if (AMODE == 0) {
      ap[i] = A + (size_t)r * K + lk;
    } else if (AMODE == 1) {
      int b = r >> 6, tt = r & 63;
      int t = t0 + tt;
      long arow = (long)b * 256 + t - SHIFT;
      if (SHIFT && t == 0) { v = false; arow = 0; }
      ap[i] = A + (size_t)arow * K + lk;
    } else {
      int b = r >> 8, t = r & 255;
      ap[i] = A + (size_t)(t + 1) * (128 * 2048) + (size_t)b * 2048 + 1024 + lk;
    }
    aval[i] = v;
  }
  const u16* wp[4];
#pragma unroll
  for (int j = 0; j < 4; ++j) wp[j] = W + (size_t)(nblk + j * 16 + lr) * K + lk;

  floatx4 zero4 = {0.f, 0.f, 0.f, 0.f};
  floatx4 acc[4][4];
#pragma unroll
  for (int i = 0; i < 4; ++i)
#pragma unroll
    for (int j = 0; j < 4; ++j) acc[i][j] = zero4;

  for (int k = 0; k < K; k += 32) {
    bf16x8 av[4], bv[4];
#pragma unroll
    for (int i = 0; i < 4; ++i) {
      bf16x8 t = *(const bf16x8*)(ap[i] + k);
      if (AMODE == 1 && SHIFT) { if (!aval[i]) t = zf; }
      av[i] = t;
    }
#pragma unroll
    for (int j = 0; j < 4; ++j) bv[j] = *(const bf16x8*)(wp[j] + k);
#pragma unroll
    for (int i = 0; i < 4; ++i)
#pragma unroll
      for (int j = 0; j < 4; ++j) acc[i][j] = MFMA16(av[i], bv[j], acc[i][j]);
  }

#pragma unroll
  for (int i = 0; i < 4; ++i) {
    int rowb = mblk + i * 16 + (lane >> 4) * 4;
#pragma unroll
    for (int j = 0; j < 4; ++j) {
      int col = nblk + j * 16 + lr;
      float bias = 0.f;
      if (b1) bias += b1[col];
      if (b2) bias += b2[col];
#pragma unroll
      for (int r = 0; r < 4; ++r) {
        float v = acc[i][j][r] + bias;
        if (ACT == 1) v = tanhf_fast(v);
        size_t off = (size_t)(rowb + r) * N + col;
        if (Cf) Cf[off] = v;
        if (Cb) Cb[off] = f2b(v);
      }
    }
  }
}

// ---------------- persistent conductor (16 steps, 64 WGs) ----------------
// WG u owns hidden cols j in [16u, 16u+16); computes all 4 gate strips for that slice.
// Waves split the 128 batch rows 4-ways (32 each). c-state stays in registers.
__global__ __launch_bounds__(256) void cond_persist(
    const float* __restrict__ gxs,   // [B*S, 4096] input proj + biases
    const u16* __restrict__ whh,     // [4096, 1024]
    u16* __restrict__ condh,         // [B*S, 1024]
    unsigned* __restrict__ bar) {
  int tid = threadIdx.x;
  int lane = tid & 63, wv = tid >> 6;
  int lr = lane & 15, lk = (lane >> 4) * 8;
  int j0 = blockIdx.x * 16;
  int j = j0 + lr;
  int mbase = wv * 32;

  const u16* wp[4];
#pragma unroll
  for (int g = 0; g < 4; ++g)
    wp[g] = whh + (size_t)(g * 1024 + j0 + lr) * 1024 + lk;

  float c[2][4];
#pragma unroll
  for (int i = 0; i < 2; ++i)
#pragma unroll
    for (int r = 0; r < 4; ++r) c[i][r] = 0.f;

  for (int s = 0; s < 16; ++s) {
    floatx4 acc[2][4];
#pragma unroll
    for (int i = 0; i < 2; ++i)
#pragma unroll
      for (int g = 0; g < 4; ++g) acc[i][g] = (floatx4){0.f, 0.f, 0.f, 0.f};
    if (s > 0) {
      const u16* a0 = condh + (size_t)((mbase + lr) * 16 + s - 1) * 1024 + lk;
      const u16* a1 = condh + (size_t)((mbase + 16 + lr) * 16 + s - 1) * 1024 + lk;
#pragma unroll 4
      for (int k = 0; k < 1024; k += 32) {
        bf16x8 av0 = *(const bf16x8*)(a0 + k);
        bf16x8 av1 = *(const bf16x8*)(a1 + k);
#pragma unroll
        for (int g = 0; g < 4; ++g) {
          bf16x8 bv = *(const bf16x8*)(wp[g] + k);
          acc[0][g] = MFMA16(av0, bv, acc[0][g]);
          acc[1][g] = MFMA16(av1, bv, acc[1][g]);
        }
      }
    }
#pragma unroll
    for (int i = 0; i < 2; ++i)
#pragma unroll
      for (int r = 0; r < 4; ++r) {
        int m = mbase + i * 16 + (lane >> 4) * 4 + r;
        const float* gx = gxs + (size_t)(m * 16 + s) * 4096 + j;
        float gi = acc[i][0][r] + gx[0];
        float gf = acc[i][1][r] + gx[1024];
        float gg = acc[i][2][r] + gx[2048];
        float go = acc[i][3][r] + gx[3072];
        float cn = sigf(gf) * c[i][r] + sigf(gi) * tanhf_fast(gg);
        c[i][r] = cn;
        condh[(size_t)(m * 16 + s) * 1024 + j] = f2b(sigf(go) * tanhf_fast(cn));
      }
    if (s < 15) gridbar(bar, 64u * (s + 1));
  }
}

// ---------------- persistent fused decoder chunk (64 steps, 128 WGs) ----------------
// hslots: [257][128][2048] bf16, slot[s] row b = [h0[s][b] | h1[s-1][b]].
// WGs 0..63  = layer0, hidden slice 16u, K=1024 vs w0hh; gates += gxbuf + embgx.
// WGs 64..127 = layer1, hidden slice 16v, K=2048 vs wcat=[W1ih|W1hh]; gates += biases.
// Phase p: L0 computes step t0+p (p<64), L1 computes step t0+p-1 (p>=1) -- 1-step skew,
// so one grid barrier per phase suffices.
__global__ __launch_bounds__(256) void dec_persist(
    const float* __restrict__ gxbuf,  // [128*64, 4096] chunk input proj (+d0 biases)
    const float* __restrict__ embgx,  // [B*S, 4096] emb @ d0_wih[:,V:]^T
    const u16* __restrict__ w0hh,     // [4096, 1024]
    const u16* __restrict__ wcat,     // [4096, 2048]
    const float* __restrict__ b1i, const float* __restrict__ b1h,
    u16* __restrict__ hsl,
    float* __restrict__ c0g, float* __restrict__ c1g,
    unsigned* __restrict__ bar, int t0) {
  const size_t SL = 128 * 2048;
  int tid = threadIdx.x;
  int lane = tid & 63, wv = tid >> 6;
  int lr = lane & 15, lk = (lane >> 4) * 8;
  int wg = blockIdx.x;
  const bool isL0 = wg < 64;
  int u = isL0 ? wg : wg - 64;
  int j0 = u * 16;
  int j = j0 + lr;
  int mbase = wv * 32;
  const int KK = isL0 ? 1024 : 2048;
  const u16* W = isL0 ? w0hh : wcat;

  const u16* wp[4];
#pragma unroll
  for (int g = 0; g < 4; ++g)
    wp[g] = W + (size_t)(g * 1024 + j0 + lr) * KK + lk;

  float b1[4] = {0.f, 0.f, 0.f, 0.f};
  if (!isL0) {
#pragma unroll
    for (int g = 0; g < 4; ++g) b1[g] = b1i[g * 1024 + j] + b1h[g * 1024 + j];
  }

  float* cg = isL0 ? c0g : c1g;
  float c[2][4];
#pragma unroll
  for (int i = 0; i < 2; ++i)
#pragma unroll
    for (int r = 0; r < 4; ++r) {
      int m = mbase + i * 16 + (lane >> 4) * 4 + r;
      c[i][r] = (t0 == 0) ? 0.f : cg[(size_t)m * 1024 + j];
    }

  for (int p = 0; p <= 64; ++p) {
    bool act = isL0 ? (p < 64) : (p >= 1);
    if (act) {
      int st = isL0 ? (t0 + p) : (t0 + p - 1);
      floatx4 acc[2][4];
#pragma unroll
      for (int i = 0; i < 2; ++i)
#pragma unroll
        for (int g = 0; g < 4; ++g) acc[i][g] = (floatx4){0.f, 0.f, 0.f, 0.f};
      if (!(isL0 && st == 0)) {
        size_t base = isL0 ? (size_t)(st - 1) * SL : (size_t)st * SL;
        const u16* a0 = hsl + base + (size_t)(mbase + lr) * 2048 + lk;
        const u16* a1 = hsl + base + (size_t)(mbase + 16 + lr) * 2048 + lk;
#pragma unroll 4
        for (int k = 0; k < KK; k += 32) {
          bf16x8 av0 = *(const bf16x8*)(a0 + k);
          bf16x8 av1 = *(const bf16x8*)(a1 + k);
#pragma unroll
          for (int g = 0; g < 4; ++g) {
            bf16x8 bv = *(const bf16x8*)(wp[g] + k);
            acc[0][g] = MFMA16(av0, bv, acc[0][g]);
            acc[1][g] = MFMA16(av1, bv, acc[1][g]);
          }
        }
      }
#pragma unroll
      for (int i = 0; i < 2; ++i)
#pragma unroll
        for (int r = 0; r < 4; ++r) {
          int m = mbase + i * 16 + (lane >> 4) * 4 + r;
          float gi, gf, gg, go;
          if (isL0) {
            const float* gx = gxbuf + (size_t)(m * 64 + p) * 4096 + j;
            const float* eg = embgx + (size_t)(m * 16 + (st >> 4)) * 4096 + j;
            gi = acc[i][0][r] + gx[0] + eg[0];
            gf = acc[i][1][r] + gx[1024] + eg[1024];
            gg = acc[i][2][r] + gx[2048] + eg[2048];
            go = acc[i][3][r] + gx[3072] + eg[3072];
          } else {
            gi = acc[i][0][r] + b1[0];
            gf = acc[i][1][r] + b1[1];
            gg = acc[i][2][r] + b1[2];
            go = acc[i][3][r] + b1[3];
          }
          float cn = sigf(gf) * c[i][r] + sigf(gi) * tanhf_fast(gg);
          c[i][r] = cn;
          u16 hb = f2b(sigf(go) * tanhf_fast(cn));
          if (isL0) hsl[(size_t)st * SL + (size_t)m * 2048 + j] = hb;
          else      hsl[(size_t)(st + 1) * SL + (size_t)m * 2048 + 1024 + j] = hb;
        }
    }
    if (p < 64) gridbar(bar, 128u * (p + 1));
  }
#pragma unroll
  for (int i = 0; i < 2; ++i)
#pragma unroll
    for (int r = 0; r < 4; ++r) {
      int m = mbase + i * 16 + (lane >> 4) * 4 + r;
      cg[(size_t)m * 1024 + j] = c[i][r];
    }
}

// ---------------- host ----------------
extern "C" void kernel_launch(void* const* d_in, const int* in_sizes, int n_in,
                              void* d_out, int out_size, void* d_ws, size_t ws_size,
                              hipStream_t stream) {
  const float* z      = (const float*)d_in[0];
  const float* x      = (const float*)d_in[1];
  const float* fcz_w  = (const float*)d_in[2];
  const float* fcz_b  = (const float*)d_in[3];
  const float* c_wih  = (const float*)d_in[4];
  const float* c_whh  = (const float*)d_in[5];
  const float* c_bih  = (const float*)d_in[6];
  const float* c_bhh  = (const float*)d_in[7];
  const float* fcc_w  = (const float*)d_in[8];
  const float* fcc_b  = (const float*)d_in[9];
  const float* d0_wih = (const float*)d_in[10];
  const float* d0_whh = (const float*)d_in[11];
  const float* d0_bih = (const float*)d_in[12];
  const float* d0_bhh = (const float*)d_in[13];
  const float* d1_wih = (const float*)d_in[14];
  const float* d1_whh = (const float*)d_in[15];
  const float* d1_bih = (const float*)d_in[16];
  const float* d1_bhh = (const float*)d_in[17];
  const float* out_w  = (const float*)d_in[18];
  const float* out_b  = (const float*)d_in[19];
  float* out = (float*)d_out;
  (void)in_sizes; (void)n_in; (void)out_size; (void)ws_size;

  char* ws = (char*)d_ws;
  size_t cur = 0;
  auto alloc = [&](size_t elems, size_t esz) -> void* {
    void* p = ws + cur;
    cur += (elems * esz + 255) & ~(size_t)255;
    return p;
  };
  u16*      wz      = (u16*)alloc(1024 * 512, 2);
  u16*      wcih    = (u16*)alloc(4096 * 1024, 2);
  u16*      wchh    = (u16*)alloc(4096 * 1024, 2);
  u16*      wfcc    = (u16*)alloc(512 * 1024, 2);
  u16*      w0v     = (u16*)alloc(4096 * 1024, 2);
  u16*      w0e     = (u16*)alloc(4096 * 512, 2);
  u16*      w0hh    = (u16*)alloc(4096 * 1024, 2);
  u16*      wcat    = (u16*)alloc((size_t)4096 * 2048, 2);
  u16*      woutw   = (u16*)alloc(1024 * 1024, 2);
  u16*      zb      = (u16*)alloc(2048 * 512, 2);
  u16*      xb      = (u16*)alloc((size_t)32768 * 1024, 2);
  u16*      condinb = (u16*)alloc(2048 * 1024, 2);
  float*    gxs     = (float*)alloc((size_t)2048 * 4096, 4);  // cond gates, then embgx
  u16*      condh   = (u16*)alloc(2048 * 1024, 2);
  u16*      embb    = (u16*)alloc(2048 * 512, 2);
  float*    gxbuf   = (float*)alloc((size_t)8192 * 4096, 4);  // chunk gate buffer (64 steps)
  u16*      hsl     = (u16*)alloc((size_t)257 * 128 * 2048, 2);
  float*    c0g     = (float*)alloc(128 * 1024, 4);
  float*    c1g     = (float*)alloc(128 * 1024, 4);
  unsigned* bar     = (unsigned*)alloc(128, 4);               // 512 B of barrier counters

  hipMemsetAsync(bar, 0, 512, stream);
  hipMemsetAsync(hsl, 0, (size_t)128 * 2048 * 2, stream);     // slot 0: h1[-1] = 0

  auto cast = [&](const float* s, u16* d, size_t n) {
    cast_f2b<<<dim3((unsigned)(n / 1024)), dim3(256), 0, stream>>>(s, d, (int)(n / 4));
  };
  cast(fcz_w, wz, (size_t)1024 * 512);
  cast(c_wih, wcih, (size_t)4096 * 1024);
  cast(c_whh, wchh, (size_t)4096 * 1024);
  cast(fcc_w, wfcc, (size_t)512 * 1024);
  cast(d0_whh, w0hh, (size_t)4096 * 1024);
  cast(out_w, woutw, (size_t)1024 * 1024);
  cast(z, zb, (size_t)2048 * 512);
  cast(x, xb, (size_t)32768 * 1024);
  cast_slice2<<<dim3(4096 * 1024 / 256), dim3(256), 0, stream>>>(d0_wih, w0v, 1536, 0, 1024, 0, 10);
  cast_slice2<<<dim3(4096 * 512 / 256), dim3(256), 0, stream>>>(d0_wih, w0e, 1536, 1024, 512, 0, 9);
  cast_slice2<<<dim3(4096 * 1024 / 256), dim3(256), 0, stream>>>(d1_wih, wcat, 1024, 0, 2048, 0, 10);
  cast_slice2<<<dim3(4096 * 1024 / 256), dim3(256), 0, stream>>>(d1_whh, wcat, 1024, 0, 2048, 1024, 10);

  // conductor input: condinb = bf16(z @ fcz_w^T + fcz_b)
  gemm_kernel<0, 0, 0><<<dim3(1024 / 128, 2048 / 128), dim3(256), 0, stream>>>(
      zb, wz, fcz_b, nullptr, nullptr, condinb, 2048, 1024, 512, 0);
  // conductor gates input proj: gxs = condin @ c_wih^T + c_bih + c_bhh
  gemm_kernel<0, 0, 0><<<dim3(4096 / 128, 2048 / 128), dim3(256), 0, stream>>>(
      condinb, wcih, c_bih, c_bhh, gxs, nullptr, 2048, 4096, 1024, 0);
  // conductor recurrence (16 steps, one persistent kernel)
  cond_persist<<<dim3(64), dim3(256), 0, stream>>>(gxs, wchh, condh, bar);
  // emb = tanh(condh @ fcc_w^T + fcc_b)
  gemm_kernel<0, 0, 1><<<dim3(512 / 128, 2048 / 128), dim3(256), 0, stream>>>(
      condh, wfcc, fcc_b, nullptr, nullptr, embb, 2048, 512, 1024, 0);
  // embgx = emb @ d0_wih[:, V:]^T  (overwrites gxs; conductor is done with it)
  gemm_kernel<0, 0, 0><<<dim3(4096 / 128, 2048 / 128), dim3(256), 0, stream>>>(
      embb, w0e, nullptr, nullptr, gxs, nullptr, 2048, 4096, 512, 0);

  // fused 2-layer decoder: per 64-step chunk, batched prev-token proj then persistent
  // pipelined recurrence (layer0 step t || layer1 step t-1 per phase).
  for (int ch = 0; ch < 4; ++ch) {
    gemm_kernel<1, 1, 0><<<dim3(4096 / 128, 8192 / 128), dim3(256), 0, stream>>>(
        xb, w0v, d0_bih, d0_bhh, gxbuf, nullptr, 8192, 4096, 1024, ch * 64);
    dec_persist<<<dim3(128), dim3(256), 0, stream>>>(
        gxbuf, gxs, w0hh, wcat, d1_bih, d1_bhh, hsl, c0g, c1g,
        bar + 16 * (1 + ch), ch * 64);
  }
  // logits = h1 @ out_w^T + out_b  (h1 read from interleaved hslots via AMODE 2)
  gemm_kernel<2, 0, 0><<<dim3(1024 / 128, 32768 / 128), dim3(256), 0, stream>>>(
      hsl, woutw, out_b, nullptr, out, nullptr, 32768, 1024, 1024, 0);
}